// Round 5
// baseline (228.357 us; speedup 1.0000x reference)
//
#include <hip/hip_runtime.h>

// GnnLayer: out[50000,64] = leaky_relu((h[idx]/dist).reshape(N,2048) @ W + bias)
// R5: BARRIER-FREE main loop. A gathered from global (bf16 h), B-fragments
// read directly from global W^T (L1/L2-hot, 64-B coalesced segments). LDS only
// holds the 9 KB meta table (idx|bf16(1/dist)) -> exactly ONE __syncthreads.
// No manual register pipelines (R4 spilled); compiler schedules 40 independent
// 16-B loads per unrolled body with fine-grained vmcnt.
// ws: [0,256KB) W^T bf16 [64][2048]; [256KB,+6.4MB) hb bf16 [50000][64]

#define N_NODES 50000
#define KN      32
#define FIN     64
#define FOUT    64
#define KDIM    2048
#define MROWS   64
#define META_STRIDE 36   // words; 144-B row stride (16-B aligned, 2-way banks)

typedef __attribute__((ext_vector_type(4))) float f32x4;
typedef __attribute__((ext_vector_type(8))) short bf16x8;

static __device__ __forceinline__ unsigned short f2b(float f) {
    union { float f; unsigned int u; } v; v.f = f;
    unsigned int u = v.u;
    return (unsigned short)((u + 0x7fffu + ((u >> 16) & 1u)) >> 16);  // RNE
}

// scale 8 bf16 by fp32: unpack pairs, mul, round-half-up, perm-pack high halves
static __device__ __forceinline__ bf16x8 scale8(bf16x8 v, float scl) {
    union U { bf16x8 h; unsigned int u[4]; };
    U in, out; in.h = v;
#pragma unroll
    for (int i = 0; i < 4; ++i) {
        unsigned int p = in.u[i];
        float lo = __builtin_bit_cast(float, p << 16);
        float hi = __builtin_bit_cast(float, p & 0xffff0000u);
        unsigned int rlo = __builtin_bit_cast(unsigned int, lo * scl) + 0x8000u;
        unsigned int rhi = __builtin_bit_cast(unsigned int, hi * scl) + 0x8000u;
        out.u[i] = __builtin_amdgcn_perm(rhi, rlo, 0x07060302u);
    }
    return out.h;
}

#define HB_BLOCKS ((N_NODES * FIN / 4) / 256)  // 3125

// fused prep: h fp32 -> bf16 ; W[2048][64] -> W^T bf16 [64][2048]
__global__ void k_prep(const float* __restrict__ h, const float* __restrict__ w,
                       unsigned short* __restrict__ hb, unsigned short* __restrict__ wt) {
    int b = blockIdx.x, tid = threadIdx.x;
    if (b < HB_BLOCKS) {
        int i = b * 256 + tid;
        float4 v = ((const float4*)h)[i];
        ushort4 p;
        p.x = f2b(v.x); p.y = f2b(v.y); p.z = f2b(v.z); p.w = f2b(v.w);
        ((ushort4*)hb)[i] = p;
    } else {
        int t = (b - HB_BLOCKS) * 256 + tid;   // 0..16383
        int n = t >> 8, kb = t & 255;
        unsigned short o[8];
#pragma unroll
        for (int j = 0; j < 8; ++j)
            o[j] = f2b(w[(kb * 8 + j) * FOUT + n]);
        *(bf16x8*)(wt + n * KDIM + kb * 8) = *(bf16x8*)o;
    }
}

__global__ __launch_bounds__(256, 4) void k_main(
        const unsigned short* __restrict__ hb,   // bf16 h [N][64]
        const float*          __restrict__ pos,  // [N][3]
        const int*            __restrict__ nidx, // [N][32]
        const unsigned short* __restrict__ wt,   // bf16 W^T [64][2048]
        const float*          __restrict__ bias, // [64]
        float*                __restrict__ out)  // [N][64]
{
    __shared__ unsigned int s_meta[MROWS * META_STRIDE];  // 9.2 KB, only LDS

    const int tid = threadIdx.x;
    const int m0  = blockIdx.x * MROWS;

    // Phase 0: pack (idx, bf16(1/dist)) per (row, kn).
    for (int p = tid; p < MROWS * KN; p += 256) {
        int row = p >> 5, kn = p & 31;
        int node = m0 + row;
        unsigned int pack = 0;
        if (node < N_NODES) {
            int idx = nidx[node * KN + kn];
            float dx = pos[node * 3 + 0] - pos[idx * 3 + 0];
            float dy = pos[node * 3 + 1] - pos[idx * 3 + 1];
            float dz = pos[node * 3 + 2] - pos[idx * 3 + 2];
            float sq = dx * dx + dy * dy + dz * dz;
            float scl = (sq == 0.f) ? 2.0f : __builtin_amdgcn_rsqf(sq);
            pack = (unsigned int)idx | ((unsigned int)f2b(scl) << 16);
        }
        s_meta[row * META_STRIDE + kn] = pack;
    }
    __syncthreads();   // the ONLY barrier

    const int wv = tid >> 6, lane = tid & 63;
    const int lm = lane & 15, q = lane >> 4;
    const int arow = wv * 16 + lm;
    const unsigned int*   mrow  = s_meta + arow * META_STRIDE;
    const unsigned short* bbase = wt + lm * KDIM + q * 8;  // + t*16*KDIM + kk*32
    const unsigned short* abase = hb + q * 8;              // + idx*64 + (kk&1)*32

    f32x4 acc[4] = {};

    unsigned int mv[4];
    *(uint4*)mv = *(const uint4*)mrow;   // kn 0..3 (covers kk 0..7)

    for (int s = 0; s < 8; ++s) {
        unsigned int m[4];
#pragma unroll
        for (int i = 0; i < 4; ++i) m[i] = mv[i];
        if (s < 7) *(uint4*)mv = *(const uint4*)(mrow + (s + 1) * 4);

#pragma unroll
        for (int kk2 = 0; kk2 < 8; ++kk2) {
            const int kk = s * 8 + kk2;
            const unsigned int meta = m[kk2 >> 1];
            const float scl = __builtin_bit_cast(float, meta & 0xffff0000u);
            bf16x8 av = *(const bf16x8*)(abase + (meta & 0xffffu) * FIN + (kk2 & 1) * 32);
            bf16x8 a  = scale8(av, scl);
#pragma unroll
            for (int t = 0; t < 4; ++t) {
                bf16x8 b = *(const bf16x8*)(bbase + t * 16 * KDIM + kk * 32);
                acc[t] = __builtin_amdgcn_mfma_f32_16x16x32_bf16(a, b, acc[t], 0, 0, 0);
            }
        }
    }

    // Epilogue: bias + leaky_relu. C/D: col=lane&15, row=q*4+reg.
#pragma unroll
    for (int t = 0; t < 4; ++t) {
        int f = t * 16 + lm;
        float bs = bias[f];
#pragma unroll
        for (int r = 0; r < 4; ++r) {
            int node = m0 + wv * 16 + q * 4 + r;
            if (node < N_NODES) {
                float v = acc[t][r] + bs;
                out[node * FOUT + f] = v > 0.f ? v : 0.01f * v;
            }
        }
    }
}

extern "C" void kernel_launch(void* const* d_in, const int* in_sizes, int n_in,
                              void* d_out, int out_size, void* d_ws, size_t ws_size,
                              hipStream_t stream) {
    const float* h    = (const float*)d_in[0];
    const float* pos  = (const float*)d_in[1];
    const int*   nidx = (const int*)d_in[2];
    const float* w    = (const float*)d_in[3];
    const float* bias = (const float*)d_in[4];
    float* out = (float*)d_out;

    unsigned short* wt = (unsigned short*)d_ws;                    // 256 KB
    unsigned short* hb = (unsigned short*)((char*)d_ws + 262144);  // 6.4 MB

    k_prep<<<HB_BLOCKS + 64, 256, 0, stream>>>(h, w, hb, wt);
    k_main<<<(N_NODES + MROWS - 1) / MROWS, 256, 0, stream>>>(hb, pos, nidx, wt, bias, out);
}

// Round 6
// 146.260 us; speedup vs baseline: 1.5613x; 1.5613x over previous
//
#include <hip/hip_runtime.h>

// GnnLayer: out[50000,64] = leaky_relu((h[idx]/dist).reshape(N,2048) @ W + bias)
// R6: R1's LDS-staged structure with measured defects fixed:
//  - ping-pong double buffer: ONE barrier per BK=64 stage (32 barriers vs 128)
//  - MROWS=32, 128-thr blocks -> grid 1563 = 6 blocks/CU (barrier-stall cover)
//  - next-stage global loads issued BEFORE current stage's MFMAs (small reg set)
//  - all LDS rows padded to 72 elems (36 words): every b128 = 8 words/bank (peak)
//  - W pre-transposed stage-major [s][n][64] -> contiguous 64 B/thread staging
// ws: [0,256KB) wt2 bf16 [32][64][64]; [256KB,+6.4MB) hb bf16 [50000][64]

#define N_NODES 50000
#define KN      32
#define FIN     64
#define FOUT    64
#define MROWS   32
#define SSTRIDE 72     // padded LDS row, elems (36 words -> conflict-free b128)
#define MSTRIDE 33

typedef __attribute__((ext_vector_type(4))) float f32x4;
typedef __attribute__((ext_vector_type(8))) short bf16x8;

static __device__ __forceinline__ unsigned short f2b(float f) {
    union { float f; unsigned int u; } v; v.f = f;
    unsigned int u = v.u;
    return (unsigned short)((u + 0x7fffu + ((u >> 16) & 1u)) >> 16);  // RNE
}

// scale 8 bf16 by fp32: unpack pairs, mul, round-half-up, perm-pack high halves
static __device__ __forceinline__ bf16x8 scale8(bf16x8 v, float scl) {
    union U { bf16x8 h; unsigned int u[4]; };
    U in, out; in.h = v;
#pragma unroll
    for (int i = 0; i < 4; ++i) {
        unsigned int p = in.u[i];
        float lo = __builtin_bit_cast(float, p << 16);
        float hi = __builtin_bit_cast(float, p & 0xffff0000u);
        unsigned int rlo = __builtin_bit_cast(unsigned int, lo * scl) + 0x8000u;
        unsigned int rhi = __builtin_bit_cast(unsigned int, hi * scl) + 0x8000u;
        out.u[i] = __builtin_amdgcn_perm(rhi, rlo, 0x07060302u);
    }
    return out.h;
}

#define HB_BLOCKS ((N_NODES * FIN / 4) / 256)  // 3125

// fused prep: h fp32 -> bf16 ; W[2048][64] -> wt2[s][n][j] = W[s*64+j][n]
__global__ void k_prep(const float* __restrict__ h, const float* __restrict__ w,
                       unsigned short* __restrict__ hb, unsigned short* __restrict__ wt2) {
    int b = blockIdx.x, tid = threadIdx.x;
    if (b < HB_BLOCKS) {
        int i = b * 256 + tid;
        float4 v = ((const float4*)h)[i];
        ushort4 p;
        p.x = f2b(v.x); p.y = f2b(v.y); p.z = f2b(v.z); p.w = f2b(v.w);
        ((ushort4*)hb)[i] = p;
    } else {
        int t = (b - HB_BLOCKS) * 256 + tid;   // 0..16383
        int d = t * 8;                          // dst elem base
        int s = d >> 12, rem = d & 4095;
        int n = rem >> 6, j0 = rem & 63;
        unsigned short o[8];
#pragma unroll
        for (int jj = 0; jj < 8; ++jj)
            o[jj] = f2b(w[(s * 64 + j0 + jj) * FOUT + n]);
        *(bf16x8*)(wt2 + d) = *(bf16x8*)o;
    }
}

__global__ __launch_bounds__(128, 4) void k_main(
        const unsigned short* __restrict__ hb,   // bf16 h [N][64]
        const float*          __restrict__ pos,  // [N][3]
        const int*            __restrict__ nidx, // [N][32]
        const unsigned short* __restrict__ wt2,  // bf16 [32 stage][64 n][64 j]
        const float*          __restrict__ bias, // [64]
        float*                __restrict__ out)  // [N][64]
{
    __shared__ __align__(16) unsigned short sA[2][MROWS * SSTRIDE]; // 9.2 KB
    __shared__ __align__(16) unsigned short sB[2][FOUT * SSTRIDE];  // 18.4 KB
    __shared__ unsigned int s_meta[MROWS * MSTRIDE];                // 4.2 KB

    const int tid = threadIdx.x;
    const int m0  = blockIdx.x * MROWS;

    // Phase 0: pack (idx, bf16(1/dist)) per (row, kn).
    for (int p = tid; p < MROWS * KN; p += 128) {
        int row = p >> 5, kn = p & 31;
        int node = m0 + row;
        unsigned int pack = 0;
        if (node < N_NODES) {
            int idx = nidx[node * KN + kn];
            float dx = pos[node * 3 + 0] - pos[idx * 3 + 0];
            float dy = pos[node * 3 + 1] - pos[idx * 3 + 1];
            float dz = pos[node * 3 + 2] - pos[idx * 3 + 2];
            float sq = dx * dx + dy * dy + dz * dz;
            float scl = (sq == 0.f) ? 2.0f : __builtin_amdgcn_rsqf(sq);
            pack = (unsigned int)idx | ((unsigned int)f2b(scl) << 16);
        }
        s_meta[row * MSTRIDE + kn] = pack;
    }
    __syncthreads();

    const int wv = tid >> 6, lane = tid & 63;
    const int lm = lane & 15, q = lane >> 4;
    const int trow = tid >> 2, part = tid & 3;   // A staging: 4 thr/row, 32 B ea
    const int brow = tid >> 1, bhalf = tid & 1;  // B staging: 2 thr/row, 64 B ea

    f32x4 acc[4] = {};

    // preload stage 0
    {
        unsigned int meta = s_meta[trow * MSTRIDE + 0];
        float scl = __builtin_bit_cast(float, meta & 0xffff0000u);
        const unsigned short* ap = hb + (meta & 0xffffu) * FIN + part * 16;
        bf16x8 a0 = *(const bf16x8*)ap;
        bf16x8 a1 = *(const bf16x8*)(ap + 8);
        const unsigned short* bp = wt2 + tid * 32;
        unsigned short* da = &sA[0][trow * SSTRIDE + part * 16];
        *(bf16x8*)(da)     = scale8(a0, scl);
        *(bf16x8*)(da + 8) = scale8(a1, scl);
        unsigned short* db = &sB[0][brow * SSTRIDE + bhalf * 32];
        *(bf16x8*)(db)      = *(const bf16x8*)(bp);
        *(bf16x8*)(db + 8)  = *(const bf16x8*)(bp + 8);
        *(bf16x8*)(db + 16) = *(const bf16x8*)(bp + 16);
        *(bf16x8*)(db + 24) = *(const bf16x8*)(bp + 24);
    }
    __syncthreads();

    for (int s = 0; s < KN; ++s) {
        const int cur = s & 1;
        const bool more = (s + 1 < KN);
        bf16x8 a0, a1, b0, b1, b2, b3;
        float scl = 0.f;
        if (more) {   // issue next-stage globals FIRST (latency covered by MFMAs)
            unsigned int meta = s_meta[trow * MSTRIDE + s + 1];
            scl = __builtin_bit_cast(float, meta & 0xffff0000u);
            const unsigned short* ap = hb + (meta & 0xffffu) * FIN + part * 16;
            a0 = *(const bf16x8*)ap;
            a1 = *(const bf16x8*)(ap + 8);
            const unsigned short* bp = wt2 + (s + 1) * 4096 + tid * 32;
            b0 = *(const bf16x8*)(bp);
            b1 = *(const bf16x8*)(bp + 8);
            b2 = *(const bf16x8*)(bp + 16);
            b3 = *(const bf16x8*)(bp + 24);
        }
        // compute stage s
#pragma unroll
        for (int kh = 0; kh < 2; ++kh) {
            bf16x8 a = *(const bf16x8*)(&sA[cur][(wv * 16 + lm) * SSTRIDE + kh * 32 + q * 8]);
#pragma unroll
            for (int t = 0; t < 4; ++t) {
                bf16x8 b = *(const bf16x8*)(&sB[cur][(t * 16 + lm) * SSTRIDE + kh * 32 + q * 8]);
                acc[t] = __builtin_amdgcn_mfma_f32_16x16x32_bf16(a, b, acc[t], 0, 0, 0);
            }
        }
        // write next stage into the other buffer
        if (more) {
            unsigned short* da = &sA[cur ^ 1][trow * SSTRIDE + part * 16];
            *(bf16x8*)(da)     = scale8(a0, scl);
            *(bf16x8*)(da + 8) = scale8(a1, scl);
            unsigned short* db = &sB[cur ^ 1][brow * SSTRIDE + bhalf * 32];
            *(bf16x8*)(db)      = b0;
            *(bf16x8*)(db + 8)  = b1;
            *(bf16x8*)(db + 16) = b2;
            *(bf16x8*)(db + 24) = b3;
            __syncthreads();   // one barrier per stage (ping-pong correctness)
        }
    }

    // Epilogue: bias + leaky_relu. C/D: col=lane&15, row=q*4+reg.
#pragma unroll
    for (int t = 0; t < 4; ++t) {
        int f = t * 16 + lm;
        float bs = bias[f];
#pragma unroll
        for (int r = 0; r < 4; ++r) {
            int node = m0 + wv * 16 + q * 4 + r;
            if (node < N_NODES) {
                float v = acc[t][r] + bs;
                out[node * FOUT + f] = v > 0.f ? v : 0.01f * v;
            }
        }
    }
}

extern "C" void kernel_launch(void* const* d_in, const int* in_sizes, int n_in,
                              void* d_out, int out_size, void* d_ws, size_t ws_size,
                              hipStream_t stream) {
    const float* h    = (const float*)d_in[0];
    const float* pos  = (const float*)d_in[1];
    const int*   nidx = (const int*)d_in[2];
    const float* w    = (const float*)d_in[3];
    const float* bias = (const float*)d_in[4];
    float* out = (float*)d_out;

    unsigned short* wt2 = (unsigned short*)d_ws;                    // 256 KB
    unsigned short* hb  = (unsigned short*)((char*)d_ws + 262144);  // 6.4 MB

    k_prep<<<HB_BLOCKS + 64, 256, 0, stream>>>(h, w, hb, wt2);
    k_main<<<(N_NODES + MROWS - 1) / MROWS, 128, 0, stream>>>(hb, pos, nidx, wt2, bias, out);
}